// Round 5
// baseline (614.629 us; speedup 1.0000x reference)
//
#include <hip/hip_runtime.h>
#include <hip/hip_bf16.h>
#include <math.h>

// 2-layer ReLU RNN, B=256, T=1000 (input 800 + zero pad), H=128, F=5.
// R5: homogeneous-wave MFMA. 256 blocks x 512 threads (8 waves). Every wave
// owns one 16-row tile of ALL THREE matvecs per step:
//   L0 : h0[s]  = relu(Whh0.h0[s-1] + Wih0.x[s] + b0)    (5 MFMA)
//   L1i: A[s-1] = Wih1.h0[s-1] + b1                       (4 MFMA, same B!)
//   L1h: h1[s-2]= relu(A[s-2] + Whh1.h1[s-3])             (4 MFMA)
// 13 MFMA/wave-step, 3 independent chains; 2 waves/SIMD = 26 MFMA = 504 cyc
// issue floor. Biases / A_f folded into MFMA C-init (no epilogue adds).
// Homogeneous waves -> balanced SIMDs + minimal barrier slop (R4 was
// phase-locked heterogeneous: both pipes idled ~2/3 of each step).
// No global memory ops inside the loop. B reads are 16B broadcasts (0 conf).
// Layouts (learn_hip m89/m91): A[m=lane&15][k=(lane>>4)*8+j];
// C/D col=lane&15, row=(lane>>4)*4+reg.

#define TT    1000
#define TIN   800
#define HD    128
#define NF    5
#define BATCH 256

typedef float f32x4 __attribute__((ext_vector_type(4)));
typedef short s16x8 __attribute__((ext_vector_type(8)));

__device__ __forceinline__ unsigned short f2bf(float f) {
    union { float f; unsigned int u; } c; c.f = f;
    unsigned int r = (c.u + 0x7FFFu + ((c.u >> 16) & 1u)) >> 16;  // RNE
    return (unsigned short)r;
}
__device__ __forceinline__ float bf2f(unsigned short h) {
    union { unsigned int u; float f; } c; c.u = ((unsigned int)h) << 16;
    return c.f;
}
__device__ __forceinline__ unsigned pk2bf(float a, float b) {
    union { __hip_bfloat162 h; unsigned u; } c;
    c.h = __float22bfloat162_rn(make_float2(a, b));   // v_cvt_pk_bf16_f32
    return c.u;
}

__global__ __launch_bounds__(512, 2) void rnn_mfma(
    const float* __restrict__ x,        // [256,800,5]
    const float* __restrict__ h_state,  // [2,256,128]
    const float* __restrict__ w_ih0,    // [128,5]
    const float* __restrict__ w_hh0,    // [128,128]
    const float* __restrict__ b_ih0,    // [128]
    const float* __restrict__ b_hh0,    // [128]
    const float* __restrict__ w_ih1,    // [128,128]
    const float* __restrict__ w_hh1,    // [128,128]
    const float* __restrict__ b_ih1,    // [128]
    const float* __restrict__ b_hh1,    // [128]
    const float* __restrict__ w_out,    // [1,128]
    const float* __restrict__ b_out,    // [1]
    float* __restrict__ out)            // [204800 y] ++ [65536 final states]
{
    __shared__ __align__(16) unsigned short x_bf[TIN * 8];  // 12.8 KB
    __shared__ __align__(16) unsigned short h0b[2][HD];
    __shared__ __align__(16) unsigned short h1b[2][HD];
    __shared__ __align__(16) float A_f[2][HD];              // pre-act + biases
    __shared__ __align__(16) unsigned short ring[16][HD];   // h1 history bf16
    __shared__ float wout_lds[HD];
    __shared__ float y_lds[TIN];                            // 3.2 KB

    const int tid = threadIdx.x;
    const int bb  = blockIdx.x;
    const int wv  = tid >> 6;       // 0..7 : row tile 16*wv
    const int l   = tid & 63;
    const int m   = l & 15;         // A row within tile / C col
    const int q4  = l >> 4;
    const bool wr = (m == 0);       // C col 0 -> writer lane
    const int row = 16 * wv + m;    // my A-fragment row
    const int r0  = 16 * wv + 4 * q4;  // my C/D row base (4 rows)

    // ---- stage x as bf16, stride 8 ----
    for (int i = tid; i < TIN * 8; i += 512) x_bf[i] = 0;
    __syncthreads();
    for (int i = tid; i < TIN * NF; i += 512) {
        int t = i / 5, f = i - 5 * t;
        x_bf[t * 8 + f] = f2bf(x[bb * (TIN * NF) + i]);
    }
    if (tid < HD) {
        h0b[0][tid] = f2bf(h_state[bb * HD + tid]);
        h1b[0][tid] = f2bf(h_state[BATCH * HD + bb * HD + tid]);
    } else if (tid < 2 * HD) {
        wout_lds[tid - HD] = w_out[tid - HD];
    }

    // ---- resident A fragments (bf16): row = 16*wv + m, k = kt*32 + q4*8 + j
    s16x8 Fhh0[4], Fih1[4], Fhh1[4], Fx;
    #pragma unroll
    for (int kt = 0; kt < 4; ++kt) {
        const float* p0 = w_hh0 + row * HD + kt * 32 + q4 * 8;
        const float* p1 = w_ih1 + row * HD + kt * 32 + q4 * 8;
        const float* p2 = w_hh1 + row * HD + kt * 32 + q4 * 8;
        s16x8 a0, a1, a2;
        #pragma unroll
        for (int j = 0; j < 8; ++j) {
            a0[j] = (short)f2bf(p0[j]);
            a1[j] = (short)f2bf(p1[j]);
            a2[j] = (short)f2bf(p2[j]);
        }
        Fhh0[kt] = a0; Fih1[kt] = a1; Fhh1[kt] = a2;
    }
    {
        s16x8 a = {0,0,0,0,0,0,0,0};
        if (q4 == 0) {
            #pragma unroll
            for (int j = 0; j < NF; ++j) a[j] = (short)f2bf(w_ih0[row * NF + j]);
        }
        Fx = a;
    }
    f32x4 bias0, bias1;
    #pragma unroll
    for (int j = 0; j < 4; ++j) {
        bias0[j] = b_ih0[r0 + j] + b_hh0[r0 + j];
        bias1[j] = b_ih1[r0 + j] + b_hh1[r0 + j];
    }
    const float bout = b_out[0];

    f32x4 hfin0 = {0,0,0,0}, hfin1 = {0,0,0,0};

    __syncthreads();

    #pragma unroll 2
    for (int s = 0; s < TT + 2; ++s) {
        const int p = s & 1;
        const int q = p ^ 1;
        const unsigned short* h0p = h0b[p];
        const unsigned short* h1p = h1b[p];

        // ---- issue all LDS reads up front ----
        s16x8 B0, B1, B2, B3, C0, C1, C2, C3, Bx;
        f32x4 pre;
        if (s <= TT) {
            B0 = *(const s16x8*)(h0p +      q4 * 8);
            B1 = *(const s16x8*)(h0p + 32 + q4 * 8);
            B2 = *(const s16x8*)(h0p + 64 + q4 * 8);
            B3 = *(const s16x8*)(h0p + 96 + q4 * 8);
        }
        if (s < TIN) Bx = *(const s16x8*)(x_bf + s * 8);
        if (s >= 2) {
            C0 = *(const s16x8*)(h1p +      q4 * 8);
            C1 = *(const s16x8*)(h1p + 32 + q4 * 8);
            C2 = *(const s16x8*)(h1p + 64 + q4 * 8);
            C3 = *(const s16x8*)(h1p + 96 + q4 * 8);
            pre = *(const f32x4*)(&A_f[p][r0]);
        }

        // ---- L0: h0[s], C-init = bias0 ----
        if (s < TT) {
            f32x4 D = bias0;
            D = __builtin_amdgcn_mfma_f32_16x16x32_bf16(Fhh0[0], B0, D, 0, 0, 0);
            D = __builtin_amdgcn_mfma_f32_16x16x32_bf16(Fhh0[1], B1, D, 0, 0, 0);
            D = __builtin_amdgcn_mfma_f32_16x16x32_bf16(Fhh0[2], B2, D, 0, 0, 0);
            D = __builtin_amdgcn_mfma_f32_16x16x32_bf16(Fhh0[3], B3, D, 0, 0, 0);
            if (s < TIN)
                D = __builtin_amdgcn_mfma_f32_16x16x32_bf16(Fx, Bx, D, 0, 0, 0);
            if (wr) {
                f32x4 v;
                #pragma unroll
                for (int j = 0; j < 4; ++j) v[j] = fmaxf(D[j], 0.f);
                *(uint2*)(h0b[q] + r0) =
                    make_uint2(pk2bf(v[0], v[1]), pk2bf(v[2], v[3]));
                if (s == TT - 1) hfin0 = v;
            }
        }

        // ---- L1-ih: A[s-1] = Wih1.h0[s-1] + b1, C-init = bias1 (same B) ----
        if (s <= TT) {
            f32x4 D = bias1;
            D = __builtin_amdgcn_mfma_f32_16x16x32_bf16(Fih1[0], B0, D, 0, 0, 0);
            D = __builtin_amdgcn_mfma_f32_16x16x32_bf16(Fih1[1], B1, D, 0, 0, 0);
            D = __builtin_amdgcn_mfma_f32_16x16x32_bf16(Fih1[2], B2, D, 0, 0, 0);
            D = __builtin_amdgcn_mfma_f32_16x16x32_bf16(Fih1[3], B3, D, 0, 0, 0);
            if (wr) *(f32x4*)(&A_f[q][r0]) = D;
        }

        // ---- L1-hh: h1[s-2] = relu(A[s-2] + Whh1.h1[s-3]), C-init = A_f ----
        if (s >= 2) {
            const int u = s - 2;
            f32x4 D = pre;
            D = __builtin_amdgcn_mfma_f32_16x16x32_bf16(Fhh1[0], C0, D, 0, 0, 0);
            D = __builtin_amdgcn_mfma_f32_16x16x32_bf16(Fhh1[1], C1, D, 0, 0, 0);
            D = __builtin_amdgcn_mfma_f32_16x16x32_bf16(Fhh1[2], C2, D, 0, 0, 0);
            D = __builtin_amdgcn_mfma_f32_16x16x32_bf16(Fhh1[3], C3, D, 0, 0, 0);
            if (wr) {
                f32x4 v;
                #pragma unroll
                for (int j = 0; j < 4; ++j) v[j] = fmaxf(D[j], 0.f);
                uint2 pk = make_uint2(pk2bf(v[0], v[1]), pk2bf(v[2], v[3]));
                *(uint2*)(h1b[q] + r0) = pk;
                if (u < TIN) *(uint2*)(ring[u & 15] + r0) = pk;
                if (u == TT - 1) hfin1 = v;
            }
        }

        // ---- batched y-dots on waves 0-3, every 8th step ----
        if (tid < 256 && s >= 10 && s <= 802 && ((s - 2) & 7) == 0) {
            const int u  = (s - 10) + (tid >> 5);
            const int l5 = tid & 31;
            const unsigned short* hr = ring[u & 15];
            float v = bf2f(hr[l5      ]) * wout_lds[l5      ]
                    + bf2f(hr[l5 + 32]) * wout_lds[l5 + 32]
                    + bf2f(hr[l5 + 64]) * wout_lds[l5 + 64]
                    + bf2f(hr[l5 + 96]) * wout_lds[l5 + 96];
            v += __shfl_xor(v, 16, 64);
            v += __shfl_xor(v,  8, 64);
            v += __shfl_xor(v,  4, 64);
            v += __shfl_xor(v,  2, 64);
            v += __shfl_xor(v,  1, 64);
            if (l5 == 0) y_lds[u] = 1.f / (1.f + expf(-(v + bout)));
        }
        __syncthreads();
    }

    // ---- epilogue: single global dump ----
    for (int i = tid; i < TIN; i += 512)
        out[bb * TIN + i] = y_lds[i];
    if (wr) {
        *(f32x4*)(out + TIN * BATCH + bb * HD + r0)              = hfin0;
        *(f32x4*)(out + TIN * BATCH + BATCH * HD + bb * HD + r0) = hfin1;
    }
}

extern "C" void kernel_launch(void* const* d_in, const int* in_sizes, int n_in,
                              void* d_out, int out_size, void* d_ws, size_t ws_size,
                              hipStream_t stream) {
    (void)in_sizes; (void)n_in; (void)d_ws; (void)ws_size; (void)out_size;
    rnn_mfma<<<dim3(BATCH), dim3(512), 0, stream>>>(
        (const float*)d_in[0],  (const float*)d_in[1],
        (const float*)d_in[2],  (const float*)d_in[3],
        (const float*)d_in[4],  (const float*)d_in[5],
        (const float*)d_in[6],  (const float*)d_in[7],
        (const float*)d_in[8],  (const float*)d_in[9],
        (const float*)d_in[10], (const float*)d_in[11],
        (float*)d_out);
}